// Round 18
// baseline (153.981 us; speedup 1.0000x reference)
//
#include <hip/hip_runtime.h>

#define NN 2048
#define AD 64
#define HH 8
#define DD 512
#define NEG 0.2f

typedef float f32x4 __attribute__((ext_vector_type(4)));
typedef _Float16 half8 __attribute__((ext_vector_type(8)));
typedef _Float16 half2v __attribute__((ext_vector_type(2)));
typedef unsigned short u16;
typedef unsigned int u32;
typedef u16 u16x8 __attribute__((ext_vector_type(8)));

// ---------------------------------------------------------------------------
// Kernel 0: prep (blocks 0..127) + vth (blocks 128..255), merged.
// Block 128 additionally zeroes the per-i-tile completion flags (stream
// ordering guarantees this lands before attn starts; re-done every call so
// graph replay is deterministic).
// ---------------------------------------------------------------------------
__global__ __launch_bounds__(256) void prep_vth_kernel(
    const float* __restrict__ Qw, const float* __restrict__ Qb,
    const float* __restrict__ Kw, const float* __restrict__ Kb,
    const float* __restrict__ A,
    const float* __restrict__ X,
    const float* __restrict__ Vw, const float* __restrict__ Vb,
    float* __restrict__ W1, float* __restrict__ W2, float* __restrict__ c12,
    u16* __restrict__ VtH, int* __restrict__ flags) {
  __shared__ float As[512][8];
  __shared__ float Ws8[8][516];
  __shared__ float red[4][8][8];
  __shared__ float red2[8][8];
  __shared__ float Xs[64][68];
  int t = threadIdx.x;
  int b = blockIdx.x;
  if (b < 128) {
    int mat = b >> 6;
    int k = (b >> 3) & 7;
    int dg = b & 7;
    int d0 = dg * 8;
    const float* Asrc = A + (size_t)k * 8192 + mat * 4096;
    const float* Wsrc = (mat ? Kw : Qw) + (size_t)d0 * DD;

    float* Asf = &As[0][0];
    for (int idx = t; idx < 4096; idx += 256) Asf[idx] = Asrc[idx];
    for (int idx = t; idx < 4096; idx += 256) {
      int dd = idx >> 9, c = idx & 511;
      Ws8[dd][c] = Wsrc[idx];
    }
    __syncthreads();

    int dd = t & 7, h = (t >> 3) & 7, cs = t >> 6;
    int cbase = cs * 128;
    float acc = 0.f;
#pragma unroll 4
    for (int c = 0; c < 128; ++c) {
      acc += Ws8[dd][cbase + c] * As[cbase + c][h];
    }
    red[cs][dd][h] = acc;
    __syncthreads();
    if (t < 64) {
      int dd2 = t >> 3, h2 = t & 7;
      float v = red[0][dd2][h2] + red[1][dd2][h2] + red[2][dd2][h2] + red[3][dd2][h2];
      (mat ? W2 : W1)[(d0 + dd2) * 64 + k * 8 + h2] = v;
    }
    if (dg == 0) {
      if (t < 64) {
        int h2 = t >> 3, seg = t & 7;
        const float* bs = mat ? Kb : Qb;
        float a2 = 0.f;
        for (int i = 0; i < 64; ++i) {
          int c = seg * 64 + i;
          a2 += bs[c] * As[c][h2];
        }
        red2[h2][seg] = a2;
      }
      __syncthreads();
      if (t < 8) {
        float s = 0.f;
#pragma unroll
        for (int seg = 0; seg < 8; ++seg) s += red2[t][seg];
        c12[mat * 64 + k * 8 + t] = s;
      }
    }
  } else {
    if (b == 128 && t < 128) flags[t] = 0;   // reset epilogue flags each call
    int tile = b - 128;
    int r0 = (tile >> 2) * 64;
    int d0 = (tile & 3) * 128;

    for (int idx = t; idx < 64 * 64; idx += 256) {
      int r = idx >> 6, c = idx & 63;
      Xs[r][c] = X[(size_t)(r0 + r) * AD + c];
    }
    __syncthreads();

    int tr = t >> 5;
    int td = t & 31;
    int d = d0 + td * 4;
    float4 bias = *(const float4*)&Vb[d];
    float4 acc[8];
#pragma unroll
    for (int i = 0; i < 8; ++i) acc[i] = bias;
    for (int c = 0; c < 64; ++c) {
      float4 w = *(const float4*)&Vw[c * DD + d];
#pragma unroll
      for (int i = 0; i < 8; ++i) {
        float x = Xs[tr * 8 + i][c];
        acc[i].x += x * w.x; acc[i].y += x * w.y;
        acc[i].z += x * w.z; acc[i].w += x * w.w;
      }
    }
#pragma unroll
    for (int c = 0; c < 4; ++c) {
      u16x8 o;
#pragma unroll
      for (int i = 0; i < 8; ++i) {
        float fv = (c == 0) ? acc[i].x : (c == 1) ? acc[i].y
                 : (c == 2) ? acc[i].z : acc[i].w;
        _Float16 hf = (_Float16)fv;
        o[i] = __builtin_bit_cast(u16, hf);
      }
      *(u16x8*)&VtH[(size_t)(d + c) * NN + r0 + tr * 8] = o;
    }
  }
}

// ---------------------------------------------------------------------------
// Kernel 1: S-tables directly from X (unchanged).
// ---------------------------------------------------------------------------
__global__ __launch_bounds__(256) void stab_kernel(
    const float* __restrict__ X,
    const float* __restrict__ W1, const float* __restrict__ W2,
    const float* __restrict__ c12,
    u16* __restrict__ TS1, u16* __restrict__ TS2) {
  __shared__ float W1L[64][65];
  __shared__ float W2L[64][65];
  __shared__ float XS[16][65];
  __shared__ __align__(16) u16 T1S[16][128];
  __shared__ __align__(16) u16 T2S[16][128];
  int t = threadIdx.x;
  int r0 = blockIdx.x * 16;
  for (int i = t; i < 4096; i += 256) {
    int d = i >> 6, kh = i & 63;
    W1L[d][kh] = W1[i];
    W2L[d][kh] = W2[i];
  }
  {
    int r = t >> 4, c = (t & 15) * 4;
    float4 xv = *(const float4*)&X[(size_t)(r0 + r) * AD + c];
    XS[r][c] = xv.x; XS[r][c + 1] = xv.y; XS[r][c + 2] = xv.z; XS[r][c + 3] = xv.w;
  }
  __syncthreads();
  int r = t >> 4, khq = t & 15;
  float a1[4], a2[4];
#pragma unroll
  for (int i = 0; i < 4; ++i) {
    a1[i] = c12[khq * 4 + i];
    a2[i] = c12[64 + khq * 4 + i];
  }
  for (int d = 0; d < 64; ++d) {
    float x = XS[r][d];
#pragma unroll
    for (int i = 0; i < 4; ++i) {
      a1[i] += x * W1L[d][khq * 4 + i];
      a2[i] += x * W2L[d][khq * 4 + i];
    }
  }
#pragma unroll
  for (int i = 0; i < 4; ++i) {
    int kh = khq * 4 + i, k = kh >> 3, h = kh & 7;
    int kki = (k ^ (r & 7)) << 4;
    _Float16 p1 = (_Float16)(__expf(a1[i]) * 0.25f);
    _Float16 n1 = (_Float16)(__expf(NEG * a1[i]) * 0.25f);
    _Float16 p2 = (_Float16)(__expf(a2[i]) * 0.25f);
    _Float16 n2 = (_Float16)(__expf(NEG * a2[i]) * 0.25f);
    T1S[r][kki + h]     = __builtin_bit_cast(u16, p1);
    T1S[r][kki + 8 + h] = __builtin_bit_cast(u16, n1);
    T2S[r][kki + h]     = __builtin_bit_cast(u16, p2);
    T2S[r][kki + 8 + h] = __builtin_bit_cast(u16, n2);
  }
  __syncthreads();
  {
    const u16* s1 = &T1S[0][0];
    const u16* s2 = &T2S[0][0];
    *(u16x8*)&TS1[(size_t)r0 * 128 + t * 8] = *(const u16x8*)&s1[t * 8];
    *(u16x8*)&TS2[(size_t)r0 * 128 + t * 8] = *(const u16x8*)&s2[t * 8];
  }
}

// ---------------------------------------------------------------------------
// Kernel 2: MFMA attention + fused projection epilogue.
// Interior identical to R15/R17 (session best). After PART/LPART stores each
// block does threadfence + atomicAdd(flags[it]); the SECOND finisher of each
// i-tile combines both j-chunks and projects rows i0..i0+15 inline (rocPRIM
// last-block pattern; device-scope atomics are XCD-safe). preS reuses the
// dead s2t LDS, linv reuses s1t. Removes the proj dispatch + one boundary.
// grid 256 = 128 i-tiles x 2 j-chunks (1024 j, 16 tiles).
// ---------------------------------------------------------------------------
__global__ __launch_bounds__(512, 4) void attn_mfma_kernel(
    const int* __restrict__ E,
    const u16* __restrict__ TS1, const u16* __restrict__ TS2,
    const u16* __restrict__ VtH,
    const float* __restrict__ Pw, const float* __restrict__ Pb,
    float* __restrict__ PART, float* __restrict__ LPART,
    int* __restrict__ flags, float* __restrict__ out) {
  __shared__ _Float16 s1t[16 * 128];        // 4 KB
  __shared__ _Float16 s2t[2][64 * 128];     // 32 KB
  __shared__ _Float16 PA[2][8][16][72];     // 36.9 KB
  __shared__ int sflag;
  int t = threadIdx.x;
  int w = t >> 6, lane = t & 63;
  int li = lane & 15, q = lane >> 4;
  int m = lane & 31;
  int i_loc = w * 2 + (lane >> 5);
  int it = blockIdx.x >> 1, ch = blockIdx.x & 1;
  int i0 = it * 16, jch = ch * 1024;

  const half8 SIX8 = {(_Float16)0.0625f, (_Float16)0.0625f, (_Float16)0.0625f,
                      (_Float16)0.0625f, (_Float16)0.0625f, (_Float16)0.0625f,
                      (_Float16)0.0625f, (_Float16)0.0625f};
  const half8 ONE8 = {(_Float16)1.0f, (_Float16)1.0f, (_Float16)1.0f,
                      (_Float16)1.0f, (_Float16)1.0f, (_Float16)1.0f,
                      (_Float16)1.0f, (_Float16)1.0f};

  if (t < 256) {
    *(u16x8*)&s1t[t * 8] = *(const u16x8*)&TS1[(size_t)i0 * 128 + t * 8];
  }
  // tile 0 -> LDS directly
  {
    const u16* src = TS2 + (size_t)jch * 128;
    *(u16x8*)&s2t[0][t * 8]        = *(const u16x8*)&src[t * 8];
    *(u16x8*)&s2t[0][4096 + t * 8] = *(const u16x8*)&src[4096 + t * 8];
  }
  // tile 1 -> staging regs
  u16x8 stA = *(const u16x8*)&TS2[(size_t)(jch + 64) * 128 + t * 8];
  u16x8 stB = *(const u16x8*)&TS2[(size_t)(jch + 64) * 128 + 4096 + t * 8];
  const int* Erow = E + (size_t)(i0 + i_loc) * NN;
  int2 eCur = *(const int2*)(Erow + jch + 2 * m);
  int2 eNxt = *(const int2*)(Erow + jch + 64 + 2 * m);
  __syncthreads();

  f32x4 acc[4];
#pragma unroll
  for (int n = 0; n < 4; ++n) acc[n] = (f32x4){0.f, 0.f, 0.f, 0.f};
  f32x4 acc_l = (f32x4){0.f, 0.f, 0.f, 0.f};
  int cur = 0;

#pragma unroll 1
  for (int jt = 0; jt < 16; ++jt) {
    int jb = jch + jt * 64;

    // depth-2: issue loads for tile jt+2 (consumed NEXT interval)
    u16x8 stA2, stB2;
    int2 eN2 = eNxt;
    if (jt < 14) {
      const u16* src = TS2 + (size_t)(jb + 128) * 128;
      stA2 = *(const u16x8*)&src[t * 8];
      stB2 = *(const u16x8*)&src[4096 + t * 8];
      eN2 = *(const int2*)(Erow + jb + 128 + 2 * m);
    }

    // bfrag loads for THIS tile
    half8 bfrag[4][2];
#pragma unroll
    for (int n = 0; n < 4; ++n)
#pragma unroll
      for (int s = 0; s < 2; ++s) {
        const u16* p = &VtH[(size_t)(w * 64 + n * 16 + li) * NN + jb + s * 32 + q * 8];
        bfrag[n][s] = *(const half8*)p;
      }

    // scores for tile jt
    const _Float16* s1row = &s1t[i_loc * 128];
    const _Float16* s2row = &s2t[cur][0];
    half8 pmj[2];
#pragma unroll
    for (int jj = 0; jj < 2; ++jj) {
      int ev = jj ? eCur.y : eCur.x;
      int j = 2 * m + jj;
      int k = min(max(ev, 0), 7);
      int kki = (k ^ (i_loc & 7)) << 4;
      int kkj = (k ^ (j & 7)) << 4;
      half8 ip = *(const half8*)&s1row[kki];
      half8 in_ = *(const half8*)&s1row[kki + 8];
      half8 jp = *(const half8*)&s2row[j * 128 + kkj];
      half8 jn = *(const half8*)&s2row[j * 128 + kkj + 8];
      half8 pp = ip * jp;
      half8 pn = in_ * jn;
      half8 pm = __builtin_elementwise_max(pp, pn);
      if (ev < 0) pm = SIX8;
      pmj[jj] = pm;
    }
#pragma unroll
    for (int h = 0; h < 8; ++h) {
      half2v wv = {pmj[0][h], pmj[1][h]};
      *(half2v*)&PA[cur][h][i_loc][2 * m] = wv;
    }

    // write tile jt+1's s2 slice; regs were loaded one interval ago
    if (jt < 15) {
      *(u16x8*)&s2t[cur ^ 1][t * 8]        = stA;
      *(u16x8*)&s2t[cur ^ 1][4096 + t * 8] = stB;
    }

    // counted-wait barrier: order LDS (PA + s2t) only; do NOT drain vmcnt
    asm volatile("s_waitcnt lgkmcnt(0)" ::: "memory");
    __builtin_amdgcn_s_barrier();

    half8 af0 = *(const half8*)&PA[cur][w][li][q * 8];
    half8 af1 = *(const half8*)&PA[cur][w][li][32 + q * 8];
    __builtin_amdgcn_s_setprio(1);
#pragma unroll
    for (int n = 0; n < 4; ++n) {
      acc[n] = __builtin_amdgcn_mfma_f32_16x16x32_f16(af0, bfrag[n][0], acc[n], 0, 0, 0);
      acc[n] = __builtin_amdgcn_mfma_f32_16x16x32_f16(af1, bfrag[n][1], acc[n], 0, 0, 0);
    }
    acc_l = __builtin_amdgcn_mfma_f32_16x16x32_f16(af0, ONE8, acc_l, 0, 0, 0);
    acc_l = __builtin_amdgcn_mfma_f32_16x16x32_f16(af1, ONE8, acc_l, 0, 0, 0);
    __builtin_amdgcn_s_setprio(0);

    stA = stA2; stB = stB2;
    eCur = eNxt; eNxt = eN2;
    cur ^= 1;
  }

  if (li == 0) {
#pragma unroll
    for (int r = 0; r < 4; ++r)
      LPART[((size_t)ch * NN + i0 + q * 4 + r) * 8 + w] = acc_l[r];
  }

  float* base = PART + (size_t)ch * NN * DD;
#pragma unroll
  for (int n = 0; n < 4; ++n) {
#pragma unroll
    for (int r = 0; r < 4; ++r) {
      int row = i0 + q * 4 + r;
      int col = w * 64 + n * 16 + li;
      base[(size_t)row * DD + col] = acc[n][r];
    }
  }

  // ---- fused projection epilogue (second finisher per i-tile) ----
  __threadfence();                      // release own PART/LPART stores
  if (t == 0) sflag = atomicAdd(&flags[it], 1);
  __syncthreads();
  if (sflag == 1) {
    __threadfence();                    // acquire partner's stores
    float* preS = (float*)&s2t[0][0];   // 16 rows x 512 = 32 KB (s2t dead)
    float* linv = (float*)&s1t[0];      // 16 x 8 (s1t dead)
    if (t < 128) {
      int i = t >> 3, h = t & 7;
      float s = LPART[(size_t)(i0 + i) * 8 + h] +
                LPART[(size_t)NN * 8 + (size_t)(i0 + i) * 8 + h];
      linv[i * 8 + h] = 1.0f / s;
    }
    __syncthreads();
    for (int idx = t; idx < 16 * 128; idx += 512) {
      int i = idx >> 7, hd = (idx & 127) * 4;
      float4 p0 = *(const float4*)&PART[(size_t)(i0 + i) * DD + hd];
      float4 p1 = *(const float4*)&PART[(size_t)NN * DD + (size_t)(i0 + i) * DD + hd];
      float li2 = linv[i * 8 + (hd >> 6)];
      float4 v;
      v.x = (p0.x + p1.x) * li2; v.y = (p0.y + p1.y) * li2;
      v.z = (p0.z + p1.z) * li2; v.w = (p0.w + p1.w) * li2;
      *(float4*)&preS[i * 512 + hd] = v;
    }
    __syncthreads();
    int c = t & 63, rq = t >> 6;        // rows rq and rq+8
    float acc0 = Pb[c], acc1 = Pb[c];
    for (int hq = 0; hq < 128; ++hq) {
      int hd = hq * 4;
      float4 pa = *(const float4*)&preS[rq * 512 + hd];
      float4 pb = *(const float4*)&preS[(rq + 8) * 512 + hd];
      float w0 = Pw[(hd + 0) * 64 + c];
      float w1 = Pw[(hd + 1) * 64 + c];
      float w2 = Pw[(hd + 2) * 64 + c];
      float w3 = Pw[(hd + 3) * 64 + c];
      acc0 += pa.x * w0 + pa.y * w1 + pa.z * w2 + pa.w * w3;
      acc1 += pb.x * w0 + pb.y * w1 + pb.z * w2 + pb.w * w3;
    }
    out[(size_t)(i0 + rq) * 64 + c] = acc0;
    out[(size_t)(i0 + rq + 8) * 64 + c] = acc1;
  }
}

// ---------------------------------------------------------------------------
extern "C" void kernel_launch(void* const* d_in, const int* in_sizes, int n_in,
                              void* d_out, int out_size, void* d_ws, size_t ws_size,
                              hipStream_t stream) {
  const float* X  = (const float*)d_in[0];
  const int*   E  = (const int*)d_in[1];
  const float* Qw = (const float*)d_in[2];
  const float* Qb = (const float*)d_in[3];
  const float* Kw = (const float*)d_in[4];
  const float* Kb = (const float*)d_in[5];
  const float* Vw = (const float*)d_in[6];
  const float* Vb = (const float*)d_in[7];
  const float* A  = (const float*)d_in[8];
  const float* Pw = (const float*)d_in[9];
  const float* Pb = (const float*)d_in[10];
  float* out = (float*)d_out;

  float* ws = (float*)d_ws;
  const size_t ND = (size_t)NN * DD;                // 1M floats
  float* PART  = ws;                                // 2 chunks x 1M floats
  u16*   TS1   = (u16*)(ws + 2 * ND);               // 512 KB
  u16*   TS2   = TS1 + (size_t)NN * 128;            // 512 KB
  u16*   VtH   = TS2 + (size_t)NN * 128;            // 2 MB
  float* LPART = (float*)(VtH + (size_t)DD * NN);   // 128 KB
  float* W1    = LPART + (size_t)2 * NN * 8;        // 16 KB
  float* W2    = W1 + 4096;                         // 16 KB
  float* c12   = W2 + 4096;                         // 512 B
  int*   flags = (int*)(c12 + 128);                 // 512 B (128 i-tiles)

  prep_vth_kernel<<<256, 256, 0, stream>>>(Qw, Qb, Kw, Kb, A, X, Vw, Vb,
                                           W1, W2, c12, VtH, flags);
  stab_kernel<<<128, 256, 0, stream>>>(X, W1, W2, c12, TS1, TS2);
  attn_mfma_kernel<<<256, 512, 0, stream>>>(E, TS1, TS2, VtH, Pw, Pb,
                                            PART, LPART, flags, out);
}

// Round 19
// 66.896 us; speedup vs baseline: 2.3018x; 2.3018x over previous
//
#include <hip/hip_runtime.h>

#define NN 2048
#define AD 64
#define HH 8
#define DD 512
#define NEG 0.2f

typedef float f32x4 __attribute__((ext_vector_type(4)));
typedef _Float16 half8 __attribute__((ext_vector_type(8)));
typedef _Float16 half2v __attribute__((ext_vector_type(2)));
typedef unsigned short u16;
typedef unsigned int u32;
typedef u16 u16x8 __attribute__((ext_vector_type(8)));

// ---------------------------------------------------------------------------
// Kernel 0: prep (blocks 0..127) + vth (blocks 128..255), merged.
// ---------------------------------------------------------------------------
__global__ __launch_bounds__(256) void prep_vth_kernel(
    const float* __restrict__ Qw, const float* __restrict__ Qb,
    const float* __restrict__ Kw, const float* __restrict__ Kb,
    const float* __restrict__ A,
    const float* __restrict__ X,
    const float* __restrict__ Vw, const float* __restrict__ Vb,
    float* __restrict__ W1, float* __restrict__ W2, float* __restrict__ c12,
    u16* __restrict__ VtH) {
  __shared__ float As[512][8];
  __shared__ float Ws8[8][516];
  __shared__ float red[4][8][8];
  __shared__ float red2[8][8];
  __shared__ float Xs[64][68];
  int t = threadIdx.x;
  int b = blockIdx.x;
  if (b < 128) {
    int mat = b >> 6;
    int k = (b >> 3) & 7;
    int dg = b & 7;
    int d0 = dg * 8;
    const float* Asrc = A + (size_t)k * 8192 + mat * 4096;
    const float* Wsrc = (mat ? Kw : Qw) + (size_t)d0 * DD;

    float* Asf = &As[0][0];
    for (int idx = t; idx < 4096; idx += 256) Asf[idx] = Asrc[idx];
    for (int idx = t; idx < 4096; idx += 256) {
      int dd = idx >> 9, c = idx & 511;
      Ws8[dd][c] = Wsrc[idx];
    }
    __syncthreads();

    int dd = t & 7, h = (t >> 3) & 7, cs = t >> 6;
    int cbase = cs * 128;
    float acc = 0.f;
#pragma unroll 4
    for (int c = 0; c < 128; ++c) {
      acc += Ws8[dd][cbase + c] * As[cbase + c][h];
    }
    red[cs][dd][h] = acc;
    __syncthreads();
    if (t < 64) {
      int dd2 = t >> 3, h2 = t & 7;
      float v = red[0][dd2][h2] + red[1][dd2][h2] + red[2][dd2][h2] + red[3][dd2][h2];
      (mat ? W2 : W1)[(d0 + dd2) * 64 + k * 8 + h2] = v;
    }
    if (dg == 0) {
      if (t < 64) {
        int h2 = t >> 3, seg = t & 7;
        const float* bs = mat ? Kb : Qb;
        float a2 = 0.f;
        for (int i = 0; i < 64; ++i) {
          int c = seg * 64 + i;
          a2 += bs[c] * As[c][h2];
        }
        red2[h2][seg] = a2;
      }
      __syncthreads();
      if (t < 8) {
        float s = 0.f;
#pragma unroll
        for (int seg = 0; seg < 8; ++seg) s += red2[t][seg];
        c12[mat * 64 + k * 8 + t] = s;
      }
    }
  } else {
    int tile = b - 128;
    int r0 = (tile >> 2) * 64;
    int d0 = (tile & 3) * 128;

    for (int idx = t; idx < 64 * 64; idx += 256) {
      int r = idx >> 6, c = idx & 63;
      Xs[r][c] = X[(size_t)(r0 + r) * AD + c];
    }
    __syncthreads();

    int tr = t >> 5;
    int td = t & 31;
    int d = d0 + td * 4;
    float4 bias = *(const float4*)&Vb[d];
    float4 acc[8];
#pragma unroll
    for (int i = 0; i < 8; ++i) acc[i] = bias;
    for (int c = 0; c < 64; ++c) {
      float4 w = *(const float4*)&Vw[c * DD + d];
#pragma unroll
      for (int i = 0; i < 8; ++i) {
        float x = Xs[tr * 8 + i][c];
        acc[i].x += x * w.x; acc[i].y += x * w.y;
        acc[i].z += x * w.z; acc[i].w += x * w.w;
      }
    }
#pragma unroll
    for (int c = 0; c < 4; ++c) {
      u16x8 o;
#pragma unroll
      for (int i = 0; i < 8; ++i) {
        float fv = (c == 0) ? acc[i].x : (c == 1) ? acc[i].y
                 : (c == 2) ? acc[i].z : acc[i].w;
        _Float16 hf = (_Float16)fv;
        o[i] = __builtin_bit_cast(u16, hf);
      }
      *(u16x8*)&VtH[(size_t)(d + c) * NN + r0 + tr * 8] = o;
    }
  }
}

// ---------------------------------------------------------------------------
// Kernel 1: S-tables directly from X (unchanged).
// ---------------------------------------------------------------------------
__global__ __launch_bounds__(256) void stab_kernel(
    const float* __restrict__ X,
    const float* __restrict__ W1, const float* __restrict__ W2,
    const float* __restrict__ c12,
    u16* __restrict__ TS1, u16* __restrict__ TS2) {
  __shared__ float W1L[64][65];
  __shared__ float W2L[64][65];
  __shared__ float XS[16][65];
  __shared__ __align__(16) u16 T1S[16][128];
  __shared__ __align__(16) u16 T2S[16][128];
  int t = threadIdx.x;
  int r0 = blockIdx.x * 16;
  for (int i = t; i < 4096; i += 256) {
    int d = i >> 6, kh = i & 63;
    W1L[d][kh] = W1[i];
    W2L[d][kh] = W2[i];
  }
  {
    int r = t >> 4, c = (t & 15) * 4;
    float4 xv = *(const float4*)&X[(size_t)(r0 + r) * AD + c];
    XS[r][c] = xv.x; XS[r][c + 1] = xv.y; XS[r][c + 2] = xv.z; XS[r][c + 3] = xv.w;
  }
  __syncthreads();
  int r = t >> 4, khq = t & 15;
  float a1[4], a2[4];
#pragma unroll
  for (int i = 0; i < 4; ++i) {
    a1[i] = c12[khq * 4 + i];
    a2[i] = c12[64 + khq * 4 + i];
  }
  for (int d = 0; d < 64; ++d) {
    float x = XS[r][d];
#pragma unroll
    for (int i = 0; i < 4; ++i) {
      a1[i] += x * W1L[d][khq * 4 + i];
      a2[i] += x * W2L[d][khq * 4 + i];
    }
  }
#pragma unroll
  for (int i = 0; i < 4; ++i) {
    int kh = khq * 4 + i, k = kh >> 3, h = kh & 7;
    int kki = (k ^ (r & 7)) << 4;
    _Float16 p1 = (_Float16)(__expf(a1[i]) * 0.25f);
    _Float16 n1 = (_Float16)(__expf(NEG * a1[i]) * 0.25f);
    _Float16 p2 = (_Float16)(__expf(a2[i]) * 0.25f);
    _Float16 n2 = (_Float16)(__expf(NEG * a2[i]) * 0.25f);
    T1S[r][kki + h]     = __builtin_bit_cast(u16, p1);
    T1S[r][kki + 8 + h] = __builtin_bit_cast(u16, n1);
    T2S[r][kki + h]     = __builtin_bit_cast(u16, p2);
    T2S[r][kki + 8 + h] = __builtin_bit_cast(u16, n2);
  }
  __syncthreads();
  {
    const u16* s1 = &T1S[0][0];
    const u16* s2 = &T2S[0][0];
    *(u16x8*)&TS1[(size_t)r0 * 128 + t * 8] = *(const u16x8*)&s1[t * 8];
    *(u16x8*)&TS2[(size_t)r0 * 128 + t * 8] = *(const u16x8*)&s2[t * 8];
  }
}

// ---------------------------------------------------------------------------
// Kernel 2: MFMA attention — R15/R17 configuration (session best, 66.9us).
// grid 256 = 128 i-tiles x 2 j-chunks (1024 j, 16 tiles).
// ---------------------------------------------------------------------------
__global__ __launch_bounds__(512, 4) void attn_mfma_kernel(
    const int* __restrict__ E,
    const u16* __restrict__ TS1, const u16* __restrict__ TS2,
    const u16* __restrict__ VtH,
    float* __restrict__ PART, float* __restrict__ LPART) {
  __shared__ _Float16 s1t[16 * 128];        // 4 KB
  __shared__ _Float16 s2t[2][64 * 128];     // 32 KB
  __shared__ _Float16 PA[2][8][16][72];     // 36.9 KB
  int t = threadIdx.x;
  int w = t >> 6, lane = t & 63;
  int li = lane & 15, q = lane >> 4;
  int m = lane & 31;
  int i_loc = w * 2 + (lane >> 5);
  int it = blockIdx.x >> 1, ch = blockIdx.x & 1;
  int i0 = it * 16, jch = ch * 1024;

  const half8 SIX8 = {(_Float16)0.0625f, (_Float16)0.0625f, (_Float16)0.0625f,
                      (_Float16)0.0625f, (_Float16)0.0625f, (_Float16)0.0625f,
                      (_Float16)0.0625f, (_Float16)0.0625f};
  const half8 ONE8 = {(_Float16)1.0f, (_Float16)1.0f, (_Float16)1.0f,
                      (_Float16)1.0f, (_Float16)1.0f, (_Float16)1.0f,
                      (_Float16)1.0f, (_Float16)1.0f};

  if (t < 256) {
    *(u16x8*)&s1t[t * 8] = *(const u16x8*)&TS1[(size_t)i0 * 128 + t * 8];
  }
  // tile 0 -> LDS directly
  {
    const u16* src = TS2 + (size_t)jch * 128;
    *(u16x8*)&s2t[0][t * 8]        = *(const u16x8*)&src[t * 8];
    *(u16x8*)&s2t[0][4096 + t * 8] = *(const u16x8*)&src[4096 + t * 8];
  }
  // tile 1 -> staging regs
  u16x8 stA = *(const u16x8*)&TS2[(size_t)(jch + 64) * 128 + t * 8];
  u16x8 stB = *(const u16x8*)&TS2[(size_t)(jch + 64) * 128 + 4096 + t * 8];
  const int* Erow = E + (size_t)(i0 + i_loc) * NN;
  int2 eCur = *(const int2*)(Erow + jch + 2 * m);
  int2 eNxt = *(const int2*)(Erow + jch + 64 + 2 * m);
  __syncthreads();

  f32x4 acc[4];
#pragma unroll
  for (int n = 0; n < 4; ++n) acc[n] = (f32x4){0.f, 0.f, 0.f, 0.f};
  f32x4 acc_l = (f32x4){0.f, 0.f, 0.f, 0.f};
  int cur = 0;

#pragma unroll 1
  for (int jt = 0; jt < 16; ++jt) {
    int jb = jch + jt * 64;

    // depth-2: issue loads for tile jt+2 (consumed NEXT interval)
    u16x8 stA2, stB2;
    int2 eN2 = eNxt;
    if (jt < 14) {
      const u16* src = TS2 + (size_t)(jb + 128) * 128;
      stA2 = *(const u16x8*)&src[t * 8];
      stB2 = *(const u16x8*)&src[4096 + t * 8];
      eN2 = *(const int2*)(Erow + jb + 128 + 2 * m);
    }

    // bfrag loads for THIS tile
    half8 bfrag[4][2];
#pragma unroll
    for (int n = 0; n < 4; ++n)
#pragma unroll
      for (int s = 0; s < 2; ++s) {
        const u16* p = &VtH[(size_t)(w * 64 + n * 16 + li) * NN + jb + s * 32 + q * 8];
        bfrag[n][s] = *(const half8*)p;
      }

    // scores for tile jt
    const _Float16* s1row = &s1t[i_loc * 128];
    const _Float16* s2row = &s2t[cur][0];
    half8 pmj[2];
#pragma unroll
    for (int jj = 0; jj < 2; ++jj) {
      int ev = jj ? eCur.y : eCur.x;
      int j = 2 * m + jj;
      int k = min(max(ev, 0), 7);
      int kki = (k ^ (i_loc & 7)) << 4;
      int kkj = (k ^ (j & 7)) << 4;
      half8 ip = *(const half8*)&s1row[kki];
      half8 in_ = *(const half8*)&s1row[kki + 8];
      half8 jp = *(const half8*)&s2row[j * 128 + kkj];
      half8 jn = *(const half8*)&s2row[j * 128 + kkj + 8];
      half8 pp = ip * jp;
      half8 pn = in_ * jn;
      half8 pm = __builtin_elementwise_max(pp, pn);
      if (ev < 0) pm = SIX8;
      pmj[jj] = pm;
    }
#pragma unroll
    for (int h = 0; h < 8; ++h) {
      half2v wv = {pmj[0][h], pmj[1][h]};
      *(half2v*)&PA[cur][h][i_loc][2 * m] = wv;
    }

    // write tile jt+1's s2 slice; regs were loaded one interval ago
    if (jt < 15) {
      *(u16x8*)&s2t[cur ^ 1][t * 8]        = stA;
      *(u16x8*)&s2t[cur ^ 1][4096 + t * 8] = stB;
    }

    // counted-wait barrier: order LDS (PA + s2t) only; do NOT drain vmcnt
    asm volatile("s_waitcnt lgkmcnt(0)" ::: "memory");
    __builtin_amdgcn_s_barrier();

    half8 af0 = *(const half8*)&PA[cur][w][li][q * 8];
    half8 af1 = *(const half8*)&PA[cur][w][li][32 + q * 8];
    __builtin_amdgcn_s_setprio(1);
#pragma unroll
    for (int n = 0; n < 4; ++n) {
      acc[n] = __builtin_amdgcn_mfma_f32_16x16x32_f16(af0, bfrag[n][0], acc[n], 0, 0, 0);
      acc[n] = __builtin_amdgcn_mfma_f32_16x16x32_f16(af1, bfrag[n][1], acc[n], 0, 0, 0);
    }
    acc_l = __builtin_amdgcn_mfma_f32_16x16x32_f16(af0, ONE8, acc_l, 0, 0, 0);
    acc_l = __builtin_amdgcn_mfma_f32_16x16x32_f16(af1, ONE8, acc_l, 0, 0, 0);
    __builtin_amdgcn_s_setprio(0);

    stA = stA2; stB = stB2;
    eCur = eNxt; eNxt = eN2;
    cur ^= 1;
  }

  if (li == 0) {
#pragma unroll
    for (int r = 0; r < 4; ++r)
      LPART[((size_t)ch * NN + i0 + q * 4 + r) * 8 + w] = acc_l[r];
  }

  float* base = PART + (size_t)ch * NN * DD;
#pragma unroll
  for (int n = 0; n < 4; ++n) {
#pragma unroll
    for (int r = 0; r < 4; ++r) {
      int row = i0 + q * 4 + r;
      int col = w * 64 + n * 16 + li;
      base[(size_t)row * DD + col] = acc[n][r];
    }
  }
}

// ---------------------------------------------------------------------------
// Kernel 3: combine 2 j-chunk partials, divide, project. grid 512, block 256.
// ---------------------------------------------------------------------------
__global__ __launch_bounds__(256) void proj_kernel(
    const float* __restrict__ PART, const float* __restrict__ LPART,
    const float* __restrict__ Pw, const float* __restrict__ Pb,
    float* __restrict__ out) {
  __shared__ __align__(16) float preS[4][512];
  __shared__ float linv[4][8];
  int t = threadIdx.x;
  int r0 = blockIdx.x * 4;
  if (t < 32) {
    int i = t >> 3, h = t & 7;
    float s = 0.f;
#pragma unroll
    for (int c = 0; c < 2; ++c)
      s += LPART[(size_t)c * NN * 8 + (size_t)(r0 + i) * 8 + h];
    linv[i][h] = 1.0f / s;
  }
  __syncthreads();
  for (int idx = t; idx < 4 * 128; idx += 256) {
    int i = idx >> 7, hd = (idx & 127) * 4;
    float4 v = {0.f, 0.f, 0.f, 0.f};
#pragma unroll
    for (int c = 0; c < 2; ++c) {
      float4 p = *(const float4*)&PART[(size_t)c * NN * DD + (size_t)(r0 + i) * DD + hd];
      v.x += p.x; v.y += p.y; v.z += p.z; v.w += p.w;
    }
    float li2 = linv[i][hd >> 6];
    v.x *= li2; v.y *= li2; v.z *= li2; v.w *= li2;
    *(float4*)&preS[i][hd] = v;
  }
  __syncthreads();
  int c = t & 63, rq = t >> 6;
  float acc0 = Pb[c];
  for (int hq = 0; hq < 128; ++hq) {
    int hd = hq * 4;
    float4 p0 = *(const float4*)&preS[rq][hd];
    float w0 = Pw[(hd + 0) * 64 + c];
    float w1 = Pw[(hd + 1) * 64 + c];
    float w2 = Pw[(hd + 2) * 64 + c];
    float w3 = Pw[(hd + 3) * 64 + c];
    acc0 += p0.x * w0 + p0.y * w1 + p0.z * w2 + p0.w * w3;
  }
  out[(size_t)(r0 + rq) * 64 + c] = acc0;
}

// ---------------------------------------------------------------------------
extern "C" void kernel_launch(void* const* d_in, const int* in_sizes, int n_in,
                              void* d_out, int out_size, void* d_ws, size_t ws_size,
                              hipStream_t stream) {
  const float* X  = (const float*)d_in[0];
  const int*   E  = (const int*)d_in[1];
  const float* Qw = (const float*)d_in[2];
  const float* Qb = (const float*)d_in[3];
  const float* Kw = (const float*)d_in[4];
  const float* Kb = (const float*)d_in[5];
  const float* Vw = (const float*)d_in[6];
  const float* Vb = (const float*)d_in[7];
  const float* A  = (const float*)d_in[8];
  const float* Pw = (const float*)d_in[9];
  const float* Pb = (const float*)d_in[10];
  float* out = (float*)d_out;

  float* ws = (float*)d_ws;
  const size_t ND = (size_t)NN * DD;                // 1M floats
  float* PART  = ws;                                // 2 chunks x 1M floats
  u16*   TS1   = (u16*)(ws + 2 * ND);               // 512 KB
  u16*   TS2   = TS1 + (size_t)NN * 128;            // 512 KB
  u16*   VtH   = TS2 + (size_t)NN * 128;            // 2 MB
  float* LPART = (float*)(VtH + (size_t)DD * NN);   // 128 KB
  float* W1    = LPART + (size_t)2 * NN * 8;        // 16 KB
  float* W2    = W1 + 4096;                         // 16 KB
  float* c12   = W2 + 4096;                         // 512 B

  prep_vth_kernel<<<256, 256, 0, stream>>>(Qw, Qb, Kw, Kb, A, X, Vw, Vb,
                                           W1, W2, c12, VtH);
  stab_kernel<<<128, 256, 0, stream>>>(X, W1, W2, c12, TS1, TS2);
  attn_mfma_kernel<<<256, 512, 0, stream>>>(E, TS1, TS2, VtH, PART, LPART);
  proj_kernel<<<512, 256, 0, stream>>>(PART, LPART, Pw, Pb, out);
}